// Round 7
// baseline (153.973 us; speedup 1.0000x reference)
//
#include <hip/hip_runtime.h>
#include <math.h>
#include <stdint.h>

#define BATCH 4
#define NSEQ 4096
#define DM 256
#define BLK 64
#define NB 64
#define TOPK 4

typedef unsigned short u16;
typedef unsigned int u32;
typedef __attribute__((ext_vector_type(8))) _Float16 f16x8;  // 8 f16 = 4 VGPR MFMA frag
typedef __attribute__((ext_vector_type(4))) float f32x4;

__device__ __forceinline__ u16 f2h(float f) {                // fp32->fp16 RTNE (v_cvt_f16_f32)
    union { _Float16 h; u16 u; } c;
    c.h = (_Float16)f;
    return c.u;
}

// ---------------- prep: centroids + Q/K fp16 cast + per-block V transpose (fp16) ----------------
// (unchanged from round 5 — passed twice)
__global__ __launch_bounds__(256) void prep_kernel(
    const float* __restrict__ q, const float* __restrict__ k, const float* __restrict__ v,
    u16* __restrict__ qf, u16* __restrict__ kf, u16* __restrict__ vtg,
    float* __restrict__ qc, float* __restrict__ kc)
{
    __shared__ u16 vt[256 * 66];                 // V^T staging, 66-pad (2-way banks max)
    const int gblk = blockIdx.x;                 // b*NB + blk
    const int d = threadIdx.x;                   // 0..255, owns one column
    const size_t base = (size_t)gblk * (BLK * DM);

    float s = 0.f;
#pragma unroll 8
    for (int r = 0; r < BLK; ++r) {              // coalesced per-row reads
        float x = q[base + (size_t)r * DM + d];
        s += x;
        qf[base + (size_t)r * DM + d] = f2h(x);
    }
    qc[(size_t)gblk * DM + d] = s * (1.f / BLK);

    s = 0.f;
#pragma unroll 8
    for (int r = 0; r < BLK; ++r) {
        float x = k[base + (size_t)r * DM + d];
        s += x;
        kf[base + (size_t)r * DM + d] = f2h(x);
    }
    kc[(size_t)gblk * DM + d] = s * (1.f / BLK);

#pragma unroll 8
    for (int r = 0; r < BLK; ++r)                // vt[d][r] = f16(V[r][d])
        vt[d * 66 + r] = f2h(v[base + (size_t)r * DM + d]);
    __syncthreads();

    // vtg[gblk][d][j] = V[j][d]: 2 rows x 32 u32 per wave-iter (in-bounds, race-free, coalesced)
    const int w = threadIdx.x >> 6, lane = threadIdx.x & 63;
    const int half = lane >> 5, c = lane & 31;
    const u32* vts = (const u32*)vt;
    u32* vo = (u32*)vtg + (base >> 1);
#pragma unroll
    for (int i = 0; i < 32; ++i) {
        int dr = w * 64 + i * 2 + half;
        vo[dr * 32 + c] = vts[dr * 33 + c];
    }
}

// ---------------- attn: fused top4 + fp16 MFMA with global A/B frags; LDS holds only P ----------
// LDS: P [64 rows][132 u32 = 264 hw] @ hw 0 (33792 B) | red[64] f32 @ hw 16896 (256 B) = 34048 B
__global__ __launch_bounds__(256, 3) void attn_kernel(
    const u16* __restrict__ qf, const u16* __restrict__ kf, const u16* __restrict__ vtg,
    const float* __restrict__ qc, const float* __restrict__ kc, float* __restrict__ out)
{
    extern __shared__ u16 smem[];
    float* red = (float*)&smem[64 * 264];        // byte 33792, 16B-aligned
    const int bid = blockIdx.x;
    const int swz = (bid & 7) * 32 + (bid >> 3); // XCD swizzle: same-batch blocks share XCD (K/V L2)
    const int b = swz >> 6, qb = swz & 63;
    const int tid = threadIdx.x;
    const int w = tid >> 6, lane = tid & 63;
    const int x = lane & 15, g = lane >> 4;      // frag coords
    const int qrow = w * 16 + x;

    // ---- Q B-frags straight from global (L2-hot; B[k=d][n=i]: lane -> i=qrow, d=dc*32+g*8+e) ----
    const u16* qfb = qf + (size_t)swz * (BLK * DM);
    f16x8 bq[8];
#pragma unroll
    for (int dc = 0; dc < 8; ++dc)
        bq[dc] = *(const f16x8*)&qfb[qrow * 256 + dc * 32 + g * 8];

    // ---- fused top-4: wave w computes dists for j = w*16..w*16+15 (coalesced 1KB reads) ----
    const float* qcp = qc + (size_t)swz * DM;
    const float* kcb = kc + (size_t)(b * NB) * DM;
    f32x4 qcv = *(const f32x4*)(qcp + lane * 4);
#pragma unroll
    for (int jj = 0; jj < 16; ++jj) {
        int j = w * 16 + jj;
        f32x4 kcv = *(const f32x4*)(kcb + (size_t)j * DM + lane * 4);
        f32x4 df = qcv - kcv;
        float s = df.x * df.x + df.y * df.y + df.z * df.z + df.w * df.w;
#pragma unroll
        for (int off = 32; off >= 1; off >>= 1) s += __shfl_xor(s, off);
        if (lane == 0) red[j] = s;               // squared dist (sqrt monotone -> same order/ties)
    }
    __syncthreads();

    int sel[TOPK];
    {
        float dval = red[lane];                  // lane = candidate j (2-way bank, free)
        for (int t = 0; t < TOPK; ++t) {         // stable iterative min: lower index wins ties
            float mv = dval;
            int mi = lane;
#pragma unroll
            for (int off = 32; off >= 1; off >>= 1) {
                float ov = __shfl_xor(mv, off);
                int oi = __shfl_xor(mi, off);
                if (ov < mv || (ov == mv && oi < mi)) { mv = ov; mi = oi; }
            }
            sel[t] = mi;                         // butterfly leaves min in all lanes (wave-uniform)
            if (lane == mi) dval = 3.0e38f;
        }
    }

    // ---- QK^T: A = K rows from GLOBAL (16B contiguous: A[m=j][k=d], lane -> j=jt*16+x) ----
    // S^T accumulators: tile kb*4+jt holds S^T[j = jt*16+g*4+r][i = qrow]
    f32x4 S[16];
#pragma unroll
    for (int t = 0; t < 16; ++t) S[t] = (f32x4){0.f, 0.f, 0.f, 0.f};

#pragma unroll
    for (int kb = 0; kb < TOPK; ++kb) {
        const u16* kfb = kf + (size_t)(b * NB + sel[kb]) * (BLK * DM);
#pragma unroll
        for (int jt = 0; jt < 4; ++jt) {
            f32x4 acc = S[kb * 4 + jt];
#pragma unroll
            for (int dc = 0; dc < 8; ++dc) {
                f16x8 ak = *(const f16x8*)&kfb[(jt * 16 + x) * 256 + dc * 32 + g * 8];
                acc = __builtin_amdgcn_mfma_f32_16x16x32_f16(ak, bq[dc], acc, 0, 0, 0);
            }
            S[kb * 4 + jt] = acc;
        }
    }

    // ---- softmax in registers: row i=qrow lives in lanes {x, x+16, x+32, x+48} ----
    float mx = -3.0e38f;
#pragma unroll
    for (int t = 0; t < 16; ++t)
#pragma unroll
        for (int r = 0; r < 4; ++r) { S[t][r] *= 0.0625f; mx = fmaxf(mx, S[t][r]); }
    mx = fmaxf(mx, __shfl_xor(mx, 16));
    mx = fmaxf(mx, __shfl_xor(mx, 32));
    float sum = 0.f;
#pragma unroll
    for (int t = 0; t < 16; ++t)
#pragma unroll
        for (int r = 0; r < 4; ++r) { float p = __expf(S[t][r] - mx); S[t][r] = p; sum += p; }
    sum += __shfl_xor(sum, 16);
    sum += __shfl_xor(sum, 32);
    const float inv = 1.f / sum;

    // ---- P (f16) -> LDS: row-major [i][j], row stride 132 u32 (same as r5: conflict-clean) ----
    u32* pw = (u32*)smem;
#pragma unroll
    for (int t = 0; t < 16; ++t)
#pragma unroll
        for (int rp = 0; rp < 2; ++rp) {
            u32 dw = (u32)f2h(S[t][2 * rp] * inv) | ((u32)f2h(S[t][2 * rp + 1] * inv) << 16);
            pw[qrow * 132 + t * 8 + g * 2 + rp] = dw;   // j = t*16 + g*4 + {0,1}/{2,3}
        }
    __syncthreads();

    // ---- PV: A = P (LDS), B = V^T rows from GLOBAL (16B contiguous: lane -> d=dt*16+x) ----
    f32x4 O[16];
#pragma unroll
    for (int t = 0; t < 16; ++t) O[t] = (f32x4){0.f, 0.f, 0.f, 0.f};

#pragma unroll
    for (int kb = 0; kb < TOPK; ++kb) {
        const u16* vtb = vtg + (size_t)(b * NB + sel[kb]) * (BLK * DM);
#pragma unroll
        for (int jc = 0; jc < 2; ++jc) {
            f16x8 pa = *(const f16x8*)&smem[qrow * 264 + kb * 64 + jc * 32 + g * 8];
#pragma unroll
            for (int dt = 0; dt < 16; ++dt) {
                f16x8 bv = *(const f16x8*)&vtb[(dt * 16 + x) * 64 + jc * 32 + g * 8];
                O[dt] = __builtin_amdgcn_mfma_f32_16x16x32_f16(pa, bv, O[dt], 0, 0, 0);
            }
        }
    }

    // ---- store: D layout row i = w*16 + g*4 + r, col d = dt*16 + x ----
    float* ob = out + ((size_t)b * NSEQ + (size_t)qb * BLK) * DM;
#pragma unroll
    for (int dt = 0; dt < 16; ++dt)
#pragma unroll
        for (int r = 0; r < 4; ++r)
            ob[(size_t)(w * 16 + g * 4 + r) * DM + dt * 16 + x] = O[dt][r];
}

extern "C" void kernel_launch(void* const* d_in, const int* in_sizes, int n_in,
                              void* d_out, int out_size, void* d_ws, size_t ws_size,
                              hipStream_t stream) {
    const float* q = (const float*)d_in[0];
    const float* k = (const float*)d_in[1];
    const float* v = (const float*)d_in[2];
    float* out = (float*)d_out;

    // ws: qf|kf|vtg (3 x 8.39MB f16) + qc|kc (2 x 256KB f32) ~= 25.7 MB
    const size_t nelem = (size_t)BATCH * NSEQ * DM;
    u16* qf = (u16*)d_ws;
    u16* kf = qf + nelem;
    u16* vtg = kf + nelem;
    float* qc = (float*)(vtg + nelem);
    float* kc = qc + (size_t)BATCH * NB * DM;

    prep_kernel<<<BATCH * NB, 256, 0, stream>>>(q, k, v, qf, kf, vtg, qc, kc);

    const int at_lds = 64 * 264 * 2 + 64 * 4;                   // 34048 B -> up to 4 WGs/CU
    hipFuncSetAttribute((const void*)attn_kernel, hipFuncAttributeMaxDynamicSharedMemorySize, at_lds);
    attn_kernel<<<BATCH * NB, 256, at_lds, stream>>>(qf, kf, vtg, qc, kc, out);
}